// Round 2
// baseline (522.809 us; speedup 1.0000x reference)
//
#include <hip/hip_runtime.h>

// CrossCueFusion on MI355X (gfx950) — round 3.
// Changes vs r2: single persistent uber-kernel (7 launches -> 1) with device-scope
// atomic grid barriers (6 phases); attention drops the ones-MFMA (l via VALU tree,
// lane-local in transposed-S layout) and interleaves exp->pack per S-half to cut
// peak VGPR below the 128 cap (was borderline-spilling under launch_bounds(256,4)).

using bf16x8 = __attribute__((ext_vector_type(8))) short;
using f32x4  = __attribute__((ext_vector_type(4))) float;
using f32x16 = __attribute__((ext_vector_type(16))) float;
typedef unsigned short u16;
typedef unsigned int   u32;

__device__ __forceinline__ u16 f2bf(float f) {  // RNE fp32 -> bf16
  u32 u = __builtin_bit_cast(u32, f);
  u = (u + 0x7fffu + ((u >> 16) & 1u)) >> 16;
  return (u16)u;
}
__device__ __forceinline__ float bf2f(u16 v) {
  u32 u = ((u32)v) << 16;
  return __builtin_bit_cast(float, u);
}
// pack two fp32 -> (bf16 hi|lo) by truncation: one v_perm_b32
__device__ __forceinline__ u32 pktr(float lo, float hi) {
  return __builtin_amdgcn_perm(__builtin_bit_cast(u32, hi),
                               __builtin_bit_cast(u32, lo), 0x07060302u);
}
__device__ __forceinline__ f32x4 mfma16(bf16x8 a, bf16x8 b, f32x4 c) {
  return __builtin_amdgcn_mfma_f32_16x16x32_bf16(a, b, c, 0, 0, 0);
}
__device__ __forceinline__ f32x16 mfma32(bf16x8 a, bf16x8 b, f32x16 c) {
  return __builtin_amdgcn_mfma_f32_32x32x16_bf16(a, b, c, 0, 0, 0);
}
__device__ __forceinline__ f32x16 zero16() {
  f32x16 z = {0,0,0,0,0,0,0,0,0,0,0,0,0,0,0,0};
  return z;
}
__device__ __forceinline__ void store4bf(u16* dst, f32x4 v) {
  u32 lo = (u32)f2bf(v[0]) | ((u32)f2bf(v[1]) << 16);
  u32 hi = (u32)f2bf(v[2]) | ((u32)f2bf(v[3]) << 16);
  *(uint2*)dst = make_uint2(lo, hi);
}
__device__ __forceinline__ float sum16(const float* e) {  // pairwise tree, depth 4
  float s0 = e[0] + e[1], s1 = e[2] + e[3], s2 = e[4] + e[5], s3 = e[6] + e[7];
  float s4 = e[8] + e[9], s5 = e[10] + e[11], s6 = e[12] + e[13], s7 = e[14] + e[15];
  float a = s0 + s1, b = s2 + s3, c = s4 + s5, d = s6 + s7;
  return (a + b) + (c + d);
}

struct UParams {
  const float* wsrc[13];
  const float *mono, *cv;
  const float *me_b1, *xe_b1, *mr_b1, *me_b2, *xe_b2;
  const float *mq_b, *mk_b, *mv_b, *xq_b, *xk_b, *xv_b;
  const float *mr_b2, *xr_b, *gamma;
  u16 *wConv, *w1x1, *monoT, *cvT, *m1T, *x1T, *r1T, *featM, *featX;
  u16 *Qm, *Km, *Vm, *Qx, *Kx, *Vx, *Opart;
  float *attA, *attB, *lpart, *dout;
  unsigned* bar;
};

// device-scope grid barrier: monotonic counter, one atomic per block, sleep-spin.
__device__ __forceinline__ void gsync(unsigned* bar, unsigned& ph) {
  ++ph;
  __syncthreads();
  if (threadIdx.x == 0) {
    __threadfence();                       // release prior writes (agent scope)
    atomicAdd(bar, 1u);
    unsigned tgt = ph * gridDim.x;
    while (__hip_atomic_load(bar, __ATOMIC_RELAXED, __HIP_MEMORY_SCOPE_AGENT) < tgt)
      __builtin_amdgcn_s_sleep(2);
    __threadfence();                       // acquire: invalidate this CU's L1
  }
  __syncthreads();
}

// ================= P0: weight prep + border zero + transpose ====================
// vb: [0,13) prep | [13,138) zero-borders | [138,4234) transpose
__device__ void pre_body(const UParams& Pp, int bx, char* smem) {
  int t = threadIdx.x;
  if (bx < 13) {
    if (bx < 6) {
      const float* s = Pp.wsrc[bx];
      u16* d = Pp.wConv + bx * 9216;  // [tap][co][ci]
      for (int i = t; i < 9216; i += 256) {
        int tap = i >> 10, co = (i >> 5) & 31, ci = i & 31;
        d[i] = f2bf(s[co * 288 + ci * 9 + tap]);
      }
    } else {
      const float* s = Pp.wsrc[bx];
      u16* d = Pp.w1x1 + (bx - 6) * 1024;
      for (int i = t; i < 1024; i += 256) d[i] = f2bf(s[i]);
    }
    return;
  }
  if (bx < 138) {
    int zb = bx - 13;
    int buf = zb % 5, blk = zb / 5;
    u16* b; int Hp, Wp;
    switch (buf) {
      case 0: b = Pp.monoT; Hp = 258; Wp = 514; break;
      case 1: b = Pp.cvT;   Hp = 258; Wp = 514; break;
      case 2: b = Pp.m1T;   Hp = 130; Wp = 258; break;
      case 3: b = Pp.x1T;   Hp = 130; Wp = 258; break;
      default: b = Pp.r1T;  Hp = 258; Wp = 514; break;
    }
    int id = blk * 256 + t;
    int cell = id >> 2, c8 = (id & 3) << 3;
    if (cell >= 2 * (Hp + Wp)) return;
    int r, c;
    if (cell < Wp)              { r = 0;                 c = cell; }
    else if (cell < 2 * Wp)     { r = Hp - 1;            c = cell - Wp; }
    else if (cell < 2 * Wp + Hp){ r = cell - 2 * Wp;     c = 0; }
    else                        { r = cell - 2 * Wp - Hp; c = Wp - 1; }
    bf16x8 z = {0, 0, 0, 0, 0, 0, 0, 0};
    *(bf16x8*)&b[(r * Wp + c) * 32 + c8] = z;
    return;
  }
  // transpose NCHW fp32 -> padded HWC bf16
  int idx = bx - 138;
  int xb = idx & 7, y = (idx >> 3) & 255, z = idx >> 11;
  const float* src = z ? Pp.cv : Pp.mono;
  u16* dst = z ? Pp.cvT : Pp.monoT;
  int x0 = xb << 6;
  u16 (*tile)[40] = (u16(*)[40])smem;
  int ci = t >> 3, kx = (t & 7) << 3;
  const float* sp = src + ci * 131072 + y * 512 + x0 + kx;
  float4 a = *(const float4*)sp;
  float4 bb = *(const float4*)(sp + 4);
  __syncthreads();  // guard LDS reuse across grid-stride iterations
  tile[kx + 0][ci] = f2bf(a.x); tile[kx + 1][ci] = f2bf(a.y);
  tile[kx + 2][ci] = f2bf(a.z); tile[kx + 3][ci] = f2bf(a.w);
  tile[kx + 4][ci] = f2bf(bb.x); tile[kx + 5][ci] = f2bf(bb.y);
  tile[kx + 6][ci] = f2bf(bb.z); tile[kx + 7][ci] = f2bf(bb.w);
  __syncthreads();
  int x = t >> 2, c8 = (t & 3) << 3;
  bf16x8 v = *(bf16x8*)&tile[x][c8];
  *(bf16x8*)(dst + ((y + 1) * 514 + (x0 + x + 1)) * 32 + c8) = v;
}

// ================= shared 3x3 conv body (16 px x 32 co per wave) ================
__device__ __forceinline__ void conv3x3_body(int bxl, int tid,
    const u16* __restrict__ inT, int Wp, const u16* __restrict__ w9,
    const float* __restrict__ bias, u16* __restrict__ out, int outPitch,
    int outOff, int Ho, int tprShift, int stride) {
  int wid = (bxl * 256 + tid) >> 6;
  int lane = tid & 63, ln = lane & 15, q = lane >> 4;
  int y = wid >> tprShift;
  int x0 = (wid & ((1 << tprShift) - 1)) << 4;
  if (y >= Ho) return;
  f32x4 acc0 = *(const f32x4*)(bias + q * 4);
  f32x4 acc1 = *(const f32x4*)(bias + 16 + q * 4);
  const u16* ib = inT + (stride * y * Wp + stride * (x0 + ln)) * 32 + q * 8;
  const u16* wb = w9 + ln * 32 + q * 8;
#pragma unroll
  for (int dy = 0; dy < 3; ++dy)
#pragma unroll
    for (int dx = 0; dx < 3; ++dx) {
      int tap = dy * 3 + dx;
      bf16x8 bf = *(const bf16x8*)(ib + (dy * Wp + dx) * 32);
      acc0 = mfma16(*(const bf16x8*)(wb + tap * 1024), bf, acc0);
      acc1 = mfma16(*(const bf16x8*)(wb + tap * 1024 + 512), bf, acc1);
    }
#pragma unroll
  for (int r = 0; r < 4; ++r) { acc0[r] = fmaxf(acc0[r], 0.f); acc1[r] = fmaxf(acc1[r], 0.f); }
  u16* ob = out + (outOff + y * outPitch + x0 + ln) * 32;
  store4bf(ob + q * 4, acc0);
  store4bf(ob + 16 + q * 4, acc1);
}

// ================= P1: the three big convs ======================================
__device__ void convs_body(const UParams& Pp, int bx) {
  if (bx < 512)
    conv3x3_body(bx, threadIdx.x, Pp.monoT, 514, Pp.wConv + 0 * 9216, Pp.me_b1, Pp.m1T, 258, 259, 128, 4, 2);
  else if (bx < 1024)
    conv3x3_body(bx - 512, threadIdx.x, Pp.cvT, 514, Pp.wConv + 2 * 9216, Pp.xe_b1, Pp.x1T, 258, 259, 128, 4, 2);
  else
    conv3x3_body(bx - 1024, threadIdx.x, Pp.monoT, 514, Pp.wConv + 4 * 9216, Pp.mr_b1, Pp.r1T, 514, 515, 256, 5, 1);
}

// ================= P2: second-stage feature convs ===============================
__device__ void feat_body(const UParams& Pp, int bx) {
  if (bx < 128)
    conv3x3_body(bx, threadIdx.x, Pp.m1T, 258, Pp.wConv + 1 * 9216, Pp.me_b2, Pp.featM, 128, 0, 64, 3, 2);
  else
    conv3x3_body(bx - 128, threadIdx.x, Pp.x1T, 258, Pp.wConv + 3 * 9216, Pp.xe_b2, Pp.featX, 128, 0, 64, 3, 2);
}

// ================= P3: q/k/v projections ========================================
__device__ void proj_body(const UParams& Pp, int vb) {
  int which = vb >> 7, bxl = vb & 127;
  const u16* feat = (which < 3) ? Pp.featM : Pp.featX;
  const float* bias; u16* dst; float scale = 1.f; int cmode = 0;
  switch (which) {
    case 0: bias = Pp.mq_b; dst = Pp.Qm; scale = 1.4426950408889634f; break;
    case 1: bias = Pp.mk_b; dst = Pp.Km; break;
    case 2: bias = Pp.mv_b; dst = Pp.Vm; cmode = 1; break;
    case 3: bias = Pp.xq_b; dst = Pp.Qx; scale = 1.4426950408889634f; break;
    case 4: bias = Pp.xk_b; dst = Pp.Kx; break;
    default: bias = Pp.xv_b; dst = Pp.Vx; cmode = 1; break;
  }
  const u16* w = Pp.w1x1 + which * 1024;
  int wave = threadIdx.x >> 6, lane = threadIdx.x & 63, ln = lane & 15, q = lane >> 4;
  int p0 = (bxl * 4 + wave) << 4;
  bf16x8 bf = *(const bf16x8*)(feat + (p0 + ln) * 32 + q * 8);
  bf16x8 a0 = *(const bf16x8*)(w + ln * 32 + q * 8);
  bf16x8 a1 = *(const bf16x8*)(w + (16 + ln) * 32 + q * 8);
  f32x4 acc0 = *(const f32x4*)(bias + q * 4);
  f32x4 acc1 = *(const f32x4*)(bias + 16 + q * 4);
  acc0 = mfma16(a0, bf, acc0);
  acc1 = mfma16(a1, bf, acc1);
#pragma unroll
  for (int r = 0; r < 4; ++r) { acc0[r] *= scale; acc1[r] *= scale; }
  if (!cmode) {  // i-major [8192][32]
    store4bf(dst + (p0 + ln) * 32 + q * 4, acc0);
    store4bf(dst + (p0 + ln) * 32 + 16 + q * 4, acc1);
  } else {       // c-major, pi-permuted within each 64-column block
    int p = p0 + ln;
    int jl = p & 63, jb = p & ~63;
    int pj = jb + (jl >> 5) * 32 + ((jl >> 4) & 1) * 16 + ((jl >> 2) & 1) * 8
           + ((jl >> 3) & 1) * 4 + (jl & 3);
#pragma unroll
    for (int r = 0; r < 4; ++r) {
      dst[(q * 4 + r) * 8192 + pj] = f2bf(acc0[r]);
      dst[(16 + q * 4 + r) * 8192 + pj] = f2bf(acc1[r]);
    }
  }
}

// ================= P4: flash attention, split-j =================================
// vb -> (ib, sp, att). l accumulated on VALU (lane-local rows in transposed-S);
// exp->pack interleaved per S-half to keep peak VGPR < 128.
__device__ void attn_body(const UParams& Pp, int vb, char* smem) {
  int ib = vb & 63, sp = (vb >> 6) & 7, att = vb >> 9;
  const u16 *Qp, *Kp, *Vp;
  if (att == 0) { Qp = Pp.Qm; Kp = Pp.Km; Vp = Pp.Vx; }   // multi_out
  else          { Qp = Pp.Qx; Kp = Pp.Kx; Vp = Pp.Vm; }   // mono_out
  int j0 = sp << 10;                                      // 1024 j per split

  typedef u16 KlT[64][40];
  typedef u16 VlT[32][72];
  KlT* Kl = (KlT*)smem;             // [2][64][40] = 10240 B
  VlT* Vl = (VlT*)(smem + 10240);   // [2][32][72] =  9216 B

  int t = threadIdx.x, wave = t >> 6, lane = t & 63, ln = lane & 31, h = lane >> 5;
  int iw = ib * 128 + wave * 32;

  bf16x8 qf0 = *(const bf16x8*)(Qp + (iw + ln) * 32 + h * 8);
  bf16x8 qf1 = *(const bf16x8*)(Qp + (iw + ln) * 32 + 16 + h * 8);

  int krow = t >> 2, kcol = (t & 3) << 3;
  int vrow = t >> 3, vcol = (t & 7) << 3;
  const u16* Kg = Kp + j0 * 32;
  const u16* Vg = Vp + j0;

  bf16x8 kn = *(const bf16x8*)(Kg + t * 8);
  bf16x8 vn = *(const bf16x8*)(Vg + vrow * 8192 + vcol);
  __syncthreads();  // guard LDS reuse across grid-stride iterations
  *(bf16x8*)&Kl[0][krow][kcol] = kn;
  *(bf16x8*)&Vl[0][vrow][vcol] = vn;

  f32x16 O = zero16();
  float lsum = 0.f;

  for (int jt = 0; jt < 16; ++jt) {
    __syncthreads();   // buf[jt&1] writes visible; prior reads of other buf done
    bool have = (jt + 1) < 16;
    if (have) {
      kn = *(const bf16x8*)(Kg + (jt + 1) * 2048 + t * 8);
      vn = *(const bf16x8*)(Vg + vrow * 8192 + (jt + 1) * 64 + vcol);
    }
    int cur = jt & 1;
    union PF { bf16x8 v; u32 w[4]; } pf[4];
    // first 32 j-rows
    f32x16 s0 = mfma32(*(const bf16x8*)&Kl[cur][ln][h * 8], qf0, zero16());
    s0 = mfma32(*(const bf16x8*)&Kl[cur][ln][16 + h * 8], qf1, s0);
    {
      float e0[16];
#pragma unroll
      for (int r = 0; r < 16; ++r) e0[r] = __builtin_amdgcn_exp2f(s0[r]);
      lsum += sum16(e0);
#pragma unroll
      for (int t2 = 0; t2 < 2; ++t2) {
        int base = t2 * 8;
#pragma unroll
        for (int p = 0; p < 4; ++p) pf[t2].w[p] = pktr(e0[base + 2 * p], e0[base + 2 * p + 1]);
      }
    }
    // second 32 j-rows
    f32x16 s1 = mfma32(*(const bf16x8*)&Kl[cur][32 + ln][h * 8], qf0, zero16());
    s1 = mfma32(*(const bf16x8*)&Kl[cur][32 + ln][16 + h * 8], qf1, s1);
    {
      float e1[16];
#pragma unroll
      for (int r = 0; r < 16; ++r) e1[r] = __builtin_amdgcn_exp2f(s1[r]);
      lsum += sum16(e1);
#pragma unroll
      for (int t2 = 2; t2 < 4; ++t2) {
        int base = (t2 & 1) * 8;
#pragma unroll
        for (int p = 0; p < 4; ++p) pf[t2].w[p] = pktr(e1[base + 2 * p], e1[base + 2 * p + 1]);
      }
    }
    // O[i][c] += P V  (matrix pipe)
#pragma unroll
    for (int t2 = 0; t2 < 4; ++t2) {
      bf16x8 vf = *(const bf16x8*)&Vl[cur][ln][t2 * 16 + h * 8];
      O = mfma32(pf[t2].v, vf, O);
    }
    if (have) {
      *(bf16x8*)&Kl[1 - cur][krow][kcol] = kn;
      *(bf16x8*)&Vl[1 - cur][vrow][vcol] = vn;
    }
  }
  // write partials: O rows i = (r&3)+8*(r>>2)+4*h, cols c = ln
  u16* ob = Pp.Opart + (size_t)(att * 8 + sp) * 262144;
  float* lb = Pp.lpart + (att * 8 + sp) * 8192;
#pragma unroll
  for (int r = 0; r < 16; ++r) {
    int ig = iw + (r & 3) + 8 * (r >> 2) + 4 * h;
    ob[ig * 32 + ln] = f2bf(O[r]);
  }
  // l[i] = lsum(lane i) + lsum(lane i+32)  (complementary j-slices mod 8)
  float lo = __shfl(lsum, lane ^ 32, 64);
  float lt = lsum + lo;
  if (lane < 32) lb[iw + lane] = lt;
}

// ================= P5: merge split partials =====================================
__device__ void reduce_body(const UParams& Pp, int vb) {
  int a = vb >> 10;
  int id = (vb & 1023) * 256 + threadIdx.x;   // 262144 per attn
  int i = id >> 5;
  float s = 0.f, l = 0.f;
#pragma unroll
  for (int sp = 0; sp < 8; ++sp) {
    s += bf2f(Pp.Opart[(size_t)(a * 8 + sp) * 262144 + id]);
    l += Pp.lpart[(a * 8 + sp) * 8192 + i];
  }
  float* out = a ? Pp.attB : Pp.attA;
  out[id] = s / l;
}

// ================= P6: final epilogues ==========================================
__device__ void final_body(const UParams& Pp, int bx) {
  int tid = threadIdx.x;
  int lane = tid & 63, ln = lane & 15, q = lane >> 4;
  float g = Pp.gamma[0];
  if (bx < 2048) {
    const u16* w9 = Pp.wConv + 5 * 9216;
    int wid = (bx * 256 + tid) >> 6;
    int y = wid >> 5, x0 = (wid & 31) << 4;
    f32x4 acc0 = *(const f32x4*)(Pp.mr_b2 + q * 4);
    f32x4 acc1 = *(const f32x4*)(Pp.mr_b2 + 16 + q * 4);
    const u16* ib = Pp.r1T + (y * 514 + x0 + ln) * 32 + q * 8;
    const u16* wb = w9 + ln * 32 + q * 8;
#pragma unroll
    for (int dy = 0; dy < 3; ++dy)
#pragma unroll
      for (int dx = 0; dx < 3; ++dx) {
        int tap = dy * 3 + dx;
        bf16x8 bf = *(const bf16x8*)(ib + (dy * 514 + dx) * 32);
        acc0 = mfma16(*(const bf16x8*)(wb + tap * 1024), bf, acc0);
        acc1 = mfma16(*(const bf16x8*)(wb + tap * 1024 + 512), bf, acc1);
      }
    int xg = x0 + ln;
    const float* ap = Pp.attA + ((y >> 2) * 128 + (xg >> 2)) * 32;
    float* ob = Pp.dout + y * 512 + xg;
#pragma unroll
    for (int r = 0; r < 4; ++r) {
      int co0 = q * 4 + r, co1 = 16 + q * 4 + r;
      ob[co0 * 131072] = fmaxf(acc0[r], 0.f) + g * ap[co0];
      ob[co1 * 131072] = fmaxf(acc1[r], 0.f) + g * ap[co1];
    }
  } else {
    const u16* w = Pp.w1x1 + 6 * 1024;
    int wid = ((bx - 2048) * 256 + tid) >> 6;
    int p0 = wid << 4;
    int y = p0 >> 9, x0 = p0 & 511;
    bf16x8 bf = *(const bf16x8*)(Pp.cvT + ((y + 1) * 514 + x0 + ln + 1) * 32 + q * 8);
    f32x4 acc0 = *(const f32x4*)(Pp.xr_b + q * 4);
    f32x4 acc1 = *(const f32x4*)(Pp.xr_b + 16 + q * 4);
    acc0 = mfma16(*(const bf16x8*)(w + ln * 32 + q * 8), bf, acc0);
    acc1 = mfma16(*(const bf16x8*)(w + (16 + ln) * 32 + q * 8), bf, acc1);
    int xg = x0 + ln;
    const float* ap = Pp.attB + ((y >> 2) * 128 + (xg >> 2)) * 32;
    float* ob = Pp.dout + 32 * 131072 + p0 + ln;
#pragma unroll
    for (int r = 0; r < 4; ++r) {
      int co0 = q * 4 + r, co1 = 16 + q * 4 + r;
      ob[co0 * 131072] = fmaxf(acc0[r], 0.f) + g * ap[co0];
      ob[co1 * 131072] = fmaxf(acc1[r], 0.f) + g * ap[co1];
    }
  }
}

// ================= uber-kernel ==================================================
__global__ void __launch_bounds__(256, 4) k_uber(UParams P) {
  __shared__ char smem[19456] __attribute__((aligned(16)));
  unsigned ph = 0;
  int nb = gridDim.x, bid = blockIdx.x;

  for (int vb = bid; vb < 4234; vb += nb) pre_body(P, vb, smem);
  gsync(P.bar, ph);
  for (int vb = bid; vb < 3072; vb += nb) convs_body(P, vb);
  gsync(P.bar, ph);
  for (int vb = bid; vb < 256; vb += nb) feat_body(P, vb);
  gsync(P.bar, ph);
  for (int vb = bid; vb < 768; vb += nb) proj_body(P, vb);
  gsync(P.bar, ph);
  for (int vb = bid; vb < 1024; vb += nb) attn_body(P, vb, smem);
  gsync(P.bar, ph);
  for (int vb = bid; vb < 2048; vb += nb) reduce_body(P, vb);
  gsync(P.bar, ph);
  for (int vb = bid; vb < 4096; vb += nb) final_body(P, vb);
}

extern "C" void kernel_launch(void* const* d_in, const int* in_sizes, int n_in,
                              void* d_out, int out_size, void* d_ws, size_t ws_size,
                              hipStream_t stream) {
  char* ws = (char*)d_ws;
  UParams P;
  P.mono  = (const float*)d_in[0];
  P.cv    = (const float*)d_in[1];
  P.me_b1 = (const float*)d_in[3];
  P.me_b2 = (const float*)d_in[5];
  P.xe_b1 = (const float*)d_in[7];
  P.xe_b2 = (const float*)d_in[9];
  P.mq_b  = (const float*)d_in[11];
  P.mk_b  = (const float*)d_in[13];
  P.mv_b  = (const float*)d_in[15];
  P.xq_b  = (const float*)d_in[17];
  P.xk_b  = (const float*)d_in[19];
  P.xv_b  = (const float*)d_in[21];
  P.mr_b1 = (const float*)d_in[23];
  P.mr_b2 = (const float*)d_in[25];
  P.xr_b  = (const float*)d_in[27];
  P.gamma = (const float*)d_in[28];
  P.dout  = (float*)d_out;

  P.wConv = (u16*)(ws + 0);         // 6 * [9][32][32] bf16
  P.w1x1  = (u16*)(ws + 110592);    // 7 * [32][32] bf16
  P.monoT = (u16*)(ws + 124928);    // [258][514][32] bf16 (dead after P1)
  P.Opart = (u16*)(ws + 124928);    // [2][8][8192][32] bf16 — reuses monoT
  P.cvT   = (u16*)(ws + 8612096);
  P.m1T   = (u16*)(ws + 17099264);  // [130][258][32]
  P.x1T   = (u16*)(ws + 19245824);
  P.r1T   = (u16*)(ws + 21392384);  // [258][514][32]
  P.featM = (u16*)(ws + 29879552);  // [8192][32]
  P.featX = (u16*)(ws + 30403840);
  P.Qm    = (u16*)(ws + 30928128);
  P.Km    = (u16*)(ws + 31452416);
  P.Vm    = (u16*)(ws + 31976704);  // [32][8192] pi-permuted
  P.Qx    = (u16*)(ws + 32500992);
  P.Kx    = (u16*)(ws + 33025280);
  P.Vx    = (u16*)(ws + 33549568);
  P.attA  = (float*)(ws + 34073856);  // multi_out [8192][32] fp32
  P.attB  = (float*)(ws + 35122432);  // mono_out
  P.lpart = (float*)(ws + 36171008);  // [2][8][8192] fp32
  P.bar   = (unsigned*)(ws + 36695296);

  P.wsrc[0] = (const float*)d_in[2];   // me_w1
  P.wsrc[1] = (const float*)d_in[4];   // me_w2
  P.wsrc[2] = (const float*)d_in[6];   // xe_w1
  P.wsrc[3] = (const float*)d_in[8];   // xe_w2
  P.wsrc[4] = (const float*)d_in[22];  // mr_w1
  P.wsrc[5] = (const float*)d_in[24];  // mr_w2
  P.wsrc[6] = (const float*)d_in[10];  // mq_w
  P.wsrc[7] = (const float*)d_in[12];  // mk_w
  P.wsrc[8] = (const float*)d_in[14];  // mv_w
  P.wsrc[9] = (const float*)d_in[16];  // xq_w
  P.wsrc[10] = (const float*)d_in[18]; // xk_w
  P.wsrc[11] = (const float*)d_in[20]; // xv_w
  P.wsrc[12] = (const float*)d_in[26]; // xr_w

  // zero the barrier counter each replay (graph-captured)
  hipMemsetAsync(P.bar, 0, 64, stream);

  // grid sized to guaranteed co-residency (launch_bounds(256,4) => 4 blocks/CU)
  int maxb = 0;
  hipOccupancyMaxActiveBlocksPerMultiprocessor(&maxb, k_uber, 256, 0);
  if (maxb <= 0) maxb = 2;          // conservative fallback, always co-resident
  if (maxb > 4) maxb = 4;
  int nb = maxb * 256;

  k_uber<<<dim3(nb), dim3(256), 0, stream>>>(P);
}